// Round 9
// baseline (2101.646 us; speedup 1.0000x reference)
//
#include <hip/hip_runtime.h>

#define B_ 128
#define T_ 256
#define L_ 4
#define DC_ 128
#define DW_ 128
#define H_ 256
#define V_ 6000
#define Z4_ 1024   // 4*H
#define S_ 4       // blocks per group (z-column split)
#define R_ 2       // batch rows per group
#define G_ 64      // groups = B/R
#define NEGF -1e30f

// d_ws layout (bytes). Stamps live inside data words — no flags, no memset.
#define WS_VTAB  4096                          // V*L*DW f32 = 12,288,000
#define WS_NH    (WS_VTAB + V_*L_*DW_*4)       // u64 [2][G][R][H]      = 512 KB
#define WS_PP    (WS_NH + (size_t)2*G_*R_*H_*8)// u64 [2][G][S][R][128] = 1 MB

typedef unsigned long long u64w;

__device__ __forceinline__ float sigm(float x) { return 1.0f / (1.0f + expf(-x)); }
__device__ __forceinline__ void pub64(u64w* p, float v, unsigned stamp) {
  u64w w = ((u64w)__float_as_uint(v) << 32) | (u64w)stamp;
  __hip_atomic_store(p, w, __ATOMIC_RELAXED, __HIP_MEMORY_SCOPE_AGENT);
}
__device__ __forceinline__ u64w ld64(const u64w* p) {
  return __hip_atomic_load(p, __ATOMIC_RELAXED, __HIP_MEMORY_SCOPE_AGENT);
}
__device__ __forceinline__ float hi32(u64w w) {
  return __uint_as_float((unsigned)(w >> 32));
}
// wave-broadcast from lane l via v_readlane (result lands in an SGPR — no VGPR cost)
__device__ __forceinline__ float bcast(float v, int l) {
  return __int_as_float(__builtin_amdgcn_readlane(__float_as_int(v), l));
}
__device__ __forceinline__ int amax4(const float* sc) {   // first-max-wins (jnp.argmax)
  float bs = sc[0]; int bw = 0;
  if (sc[1] > bs) { bs = sc[1]; bw = 1; }
  if (sc[2] > bs) { bs = sc[2]; bw = 2; }
  if (sc[3] > bs) { bs = sc[3]; bw = 3; }
  return bw;
}
__device__ __forceinline__ float invlen(int w) {
  return (w == 0) ? 1.0f : (w == 1) ? 0.5f : (w == 2) ? (1.0f / 3.0f) : 0.25f;
}

// ------------------------------------------------------------------
// Kernel 1: vocab composition table (unchanged — verified).
// ------------------------------------------------------------------
__global__ __launch_bounds__(512) void vtab_kernel(
    const float* __restrict__ char_emb, const float* __restrict__ reset_W,
    const float* __restrict__ reset_b, const float* __restrict__ com_W,
    const float* __restrict__ com_b, float* __restrict__ Vtab)
{
  const int v = blockIdx.x;
  const int tid = threadIdx.x;
  const int w = tid >> 7;
  const int e = tid & 127;
  __shared__ float emb[DC_];
  __shared__ float ge[L_][DC_];
  if (tid < DC_) emb[tid] = char_emb[v * DC_ + tid];
  __syncthreads();
  float acc = reset_b[w * DC_ + e];
  const float* W = reset_W + (size_t)w * DC_ * DC_;
  #pragma unroll 8
  for (int k = 0; k < DC_; ++k) acc = fmaf(emb[k], W[k * DC_ + e], acc);
  ge[w][e] = sigm(acc) * emb[e];
  __syncthreads();
  float acc2 = com_b[e];
  #pragma unroll 8
  for (int k = 0; k < DC_; ++k) acc2 = fmaf(ge[w][k], com_W[k * DW_ + e], acc2);
  Vtab[((size_t)v * L_ + w) * DW_ + e] = tanhf(acc2);
}

// ------------------------------------------------------------------
// Kernel 2: distributed scan, S=4 x R=2, blk = s*64+g, 512 threads.
// R8 verified base (floor 1863us; 2 barriers/step, scores hoisted
// into S0, LDS poll-relay dedup).
// THIS ROUND (R9): overlap zh with zx. In R8, B1 serialized the
// upper waves' 768-inst zh (needs only nh, arrives early) against
// the lower waves' vtsel+zx (needs pp->pred->scores) even though
// they are parallel dataflow branches converging only at the gates.
// Now: S0 upper = w4 polls the 6 nh words and relays payloads to
// nhUpL only (w5-7 idle); after B1 the upper waves run the ENTIRE
// zh from nhUpL (same bits, same j/k chain order -> bit-identical)
// and write zring = zhA + z inline, concurrently with the lower
// waves' vtsel+zx in the same barrier window. stampUp and zhB are
// gone: B1 orders relay->read, and w4 cannot overwrite nhUpL at
// t+1 before B2(t) (no WAR race). All accumulation chains and
// publish/poll structure unchanged.
// ------------------------------------------------------------------
__global__ __launch_bounds__(512, 2) void seq_kernel(
    const int* __restrict__ chars, const float* __restrict__ Vtab,
    const float* __restrict__ Kmat, const float* __restrict__ lstm_bias,
    const float* __restrict__ pred_W, const float* __restrict__ pred_b,
    const float* __restrict__ score_U, const float* __restrict__ bos,
    float* __restrict__ out, u64w* __restrict__ nh_mb, u64w* __restrict__ pp_mb)
{
  const int blk = blockIdx.x;
  const int s = blk >> 6;      // 0..3 column-split (partners stride 64 -> same XCD %8)
  const int g = blk & 63;      // group id
  const int tid = threadIdx.x;
  const int lane = tid & 63;
  const int wv = tid >> 6;
  const int c = tid & 255;     // my z-column (local)
  const int koff = (tid < 256) ? 0 : 192;
  const int colg = (c >> 6) * H_ + s * 64 + (c & 63);  // global z-column
  const int row0 = g * R_;

  // ---- weight registers: K[koff+i][colg], i = 0..191 ----
  float wreg[192];
  #pragma unroll
  for (int i = 0; i < 192; ++i)
    wreg[i] = Kmat[(size_t)(koff + i) * Z4_ + colg];

  __shared__ float ringVt[R_][4][512];      // 16 KB
  __shared__ float pring[4][R_][DW_];       // 4 KB
  __shared__ float zring[4][R_][256];       // 8 KB (also bos z scratch)
  __shared__ float cring[4][R_][64];        // 2 KB
  __shared__ float zhA[R_][256];            // 2 KB (lower zh partials; bos scratch)
  __shared__ float zxL[R_][256];            // 2 KB
  __shared__ float predWL[64][128];         // 32 KB (my pred_W slice)
  __shared__ float h1tmp[H_];               // 1 KB (init only)
  __shared__ int   charsL[R_][T_];          // 2 KB
  __shared__ float biasC[256], UL[128], pbL[128];
  __shared__ float scL[R_][L_];
  // LDS relay for deduped polls
  __shared__ float nhLowL[2][64];           // 0.5 KB (w0-relayed nh h[0:64])
  __shared__ float nhUpL[6][64];            // 1.5 KB (w4-relayed nh h[64:256])
  __shared__ int   stampLow;
  __shared__ float bosZh[512];              // 2 KB (bos-only scratch)

  // ---- one-time loads ----
  if (tid == 0) { stampLow = 0; }
  if (tid < 256) biasC[tid] = lstm_bias[(tid >> 6) * H_ + s * 64 + (tid & 63)];
  if (tid < 128) { UL[tid] = score_U[tid]; pbL[tid] = pred_b[tid]; }
  for (int i = tid; i < 64 * 128; i += 512)
    predWL[i >> 7][i & 127] = pred_W[(size_t)(s * 64 + (i >> 7)) * DW_ + (i & 127)];
  for (int i = tid; i < R_ * T_; i += 512)
    charsL[i >> 8][i & 255] = chars[(row0 + (i >> 8)) * T_ + (i & 255)];
  for (int i = tid; i < R_ * 4 * 512; i += 512) ((float*)ringVt)[i] = 0.0f;
  __syncthreads();

  // ---- bos step (x=bos, c0=h0=0): h1/c1, pred0, zh1 ----
  {
    float* zb = &zring[0][0][0];   // 1024-float scratch (slots 0-1)
    for (int c2 = tid; c2 < Z4_; c2 += 512) {
      float a = lstm_bias[c2];
      #pragma unroll 8
      for (int k = 0; k < DC_; ++k) a = fmaf(bos[k], Kmat[(size_t)k * Z4_ + c2], a);
      zb[c2] = a;
    }
    __syncthreads();
    if (tid < H_) {
      float zi = zb[tid], zj = zb[H_ + tid], zo = zb[3 * H_ + tid];
      float nc = sigm(zi) * tanhf(zj);
      float nh = tanhf(nc) * sigm(zo);
      h1tmp[tid] = nh;
      int hl = tid - s * 64;
      if (hl >= 0 && hl < 64) {
        #pragma unroll
        for (int q = 0; q < 4; ++q)
          #pragma unroll
          for (int r = 0; r < R_; ++r) cring[q][r][hl] = nc;
      }
    }
    __syncthreads();
    { // pred0 partials into zhA scratch (512 floats)
      int kq = tid >> 7, e = tid & 127;
      float a = 0.0f;
      #pragma unroll 8
      for (int k = kq * 64; k < kq * 64 + 64; ++k)
        a = fmaf(h1tmp[k], pred_W[(size_t)k * DW_ + e], a);
      ((float*)zhA)[kq * 128 + e] = a;
    }
    __syncthreads();
    if (tid < 128) {
      const float* pa = (const float*)zhA;
      float p = tanhf(pbL[tid] + pa[tid] + pa[128 + tid] + pa[256 + tid] + pa[384 + tid]);
      #pragma unroll
      for (int q = 0; q < 4; ++q)
        #pragma unroll
        for (int r = 0; r < R_; ++r) pring[q][r][tid] = p;
    }
    __syncthreads();   // pred0 partials consumed; zb consumed (h1 extracted)
    { // zh1 = Kh @ h1 via register weights (h1 same for both rows)
      float a = 0.0f;
      if (tid < 256) {
        #pragma unroll
        for (int k = 0; k < 64; ++k) a = fmaf(h1tmp[k], wreg[128 + k], a);
      } else {
        #pragma unroll
        for (int k = 0; k < 192; ++k) a = fmaf(h1tmp[64 + k], wreg[k], a);
      }
      __syncthreads();
      bosZh[(tid < 256 ? 0 : 256) + c] = a;
    }
    __syncthreads();
    if (tid < 256) {
      float z1 = bosZh[tid] + bosZh[256 + tid];
      #pragma unroll
      for (int q = 0; q < 4; ++q)
        #pragma unroll
        for (int r = 0; r < R_; ++r) zring[q][r][tid] = z1;
    }
    __syncthreads();
  }

  // ---- scan ----
  for (int t = 0; t < T_; ++t) {
    const int slot = t & 3;
    const int parR = (t - 1) & 1;
    const int parW = t & 1;
    const unsigned stR = (unsigned)t;
    const unsigned stW = (unsigned)(t + 1);

    // ===== S0: polls + relays + zhA + pred + ALL scores =====
    if (wv < 2) {
      // w0/w1: nh poll (w0 relays) + zhA + pp poll + pred + score (r,0)
      const int r = wv;
      const float* vp0 = Vtab + (size_t)charsL[r][t] * 512;
      float vva = vp0[lane];          // c2=0 term, e=lane   (same bits as gather)
      float vvb = vp0[64 + lane];     // c2=0 term, e=lane+64
      if (t > 0) {
        const u64w* nb = nh_mb + ((size_t)parR * G_ + g) * (R_ * H_);
        u64w nw0, nw1;
        for (;;) {
          nw0 = ld64(nb + lane);
          nw1 = ld64(nb + H_ + lane);
          int ok = ((unsigned)nw0 == stR) & ((unsigned)nw1 == stR);
          if (__all(ok)) break;
          __builtin_amdgcn_s_sleep(1);
        }
        float nv0 = hi32(nw0), nv1 = hi32(nw1);
        if (wv == 0) {   // relay payloads to w2-3 (exact bits)
          nhLowL[0][lane] = nv0;
          nhLowL[1][lane] = nv1;
          __hip_atomic_store(&stampLow, (int)t, __ATOMIC_RELEASE,
                             __HIP_MEMORY_SCOPE_WORKGROUP);
        }
        // zh(t-1) partial over h[0:64] via register weights (needs only nh)
        float z0 = 0.0f, z1 = 0.0f;
        #pragma unroll
        for (int k = 0; k < 64; ++k) {
          float w = wreg[128 + k];
          z0 = fmaf(bcast(nv0, k), w, z0);
          z1 = fmaf(bcast(nv1, k), w, z1);
        }
        zhA[0][c] = z0; zhA[1][c] = z1;
        // pp poll (partners publish pp ~400cy after nh; usually arrived)
        const u64w* ppb = pp_mb + ((size_t)parR * G_ + g) * (S_ * R_ * 128) + wv * 128;
        u64w pw0[S_], pw1[S_];
        for (;;) {
          #pragma unroll
          for (int sp = 0; sp < S_; ++sp) {
            pw0[sp] = ld64(ppb + (size_t)sp * (R_ * 128) + lane);
            pw1[sp] = ld64(ppb + (size_t)sp * (R_ * 128) + lane + 64);
          }
          int ok = 1;
          #pragma unroll
          for (int sp = 0; sp < S_; ++sp)
            ok &= ((unsigned)pw0[sp] == stR) & ((unsigned)pw1[sp] == stR);
          if (__all(ok)) break;
          __builtin_amdgcn_s_sleep(1);
        }
        // pred(t-1) for row r=wv (sum order = sp 0..3, matches prior rounds)
        float a0 = pbL[lane], a1 = pbL[lane + 64];
        #pragma unroll
        for (int sp = 0; sp < S_; ++sp) {
          a0 += hi32(pw0[sp]);
          a1 += hi32(pw1[sp]);
        }
        int ps = (t - 1) & 3;
        pring[ps][wv][lane] = tanhf(a0);
        pring[ps][wv][lane + 64] = tanhf(a1);
      }
      { // score (r, w=0): needs only pring[(t-1)&3][r] (own wave) + vva/vvb
        int ps = (t - 1) & 3;
        float il = invlen(0);
        float acc = 0.0f;
        { float sa = vva;
          acc = fmaf(pring[ps][r][lane] + UL[lane], sa * il, acc); }
        { float sa = vvb;
          acc = fmaf(pring[ps][r][lane + 64] + UL[lane + 64], sa * il, acc); }
        #pragma unroll
        for (int off = 32; off; off >>= 1) acc += __shfl_down(acc, off);
        if (lane == 0) scL[r][0] = acc;    // w=0 <= t always
      }
    } else if (wv < 4) {
      // w2-3: Vt gather (LDS, both rows) + scores (rsc, w=1..3) hidden
      // under the relay wait, then zhA.
      const int rsc = wv - 2;
      int i2 = tid & 127;
      #pragma unroll
      for (int r = 0; r < R_; ++r) {
        const float* vp = Vtab + (size_t)charsL[r][t] * 512;
        #pragma unroll
        for (int q = 0; q < 4; ++q) ringVt[r][slot][q * 128 + i2] = vp[q * 128 + i2];
      }
      // register copies of the c2=0 terms for my score row (same bits)
      const float* vpr = Vtab + (size_t)charsL[rsc][t] * 512;
      float va[3], vb[3];
      #pragma unroll
      for (int w = 1; w <= 3; ++w) {
        va[w - 1] = vpr[w * 128 + lane];
        vb[w - 1] = vpr[w * 128 + 64 + lane];
      }
      // scores (rsc, w=1..3): read only prev-step pring/ringVt slots
      #pragma unroll
      for (int w = 1; w <= 3; ++w) {
        int ps = (t - 1 - w) & 3;
        float il = invlen(w);
        float acc = 0.0f;
        { float sa = va[w - 1];
          #pragma unroll
          for (int c2 = 1; c2 < L_; ++c2)
            if (c2 <= w) sa += ringVt[rsc][(t - c2) & 3][w * 128 + lane];
          acc = fmaf(pring[ps][rsc][lane] + UL[lane], sa * il, acc); }
        { float sa = vb[w - 1];
          #pragma unroll
          for (int c2 = 1; c2 < L_; ++c2)
            if (c2 <= w) sa += ringVt[rsc][(t - c2) & 3][w * 128 + 64 + lane];
          acc = fmaf(pring[ps][rsc][lane + 64] + UL[lane + 64], sa * il, acc); }
        #pragma unroll
        for (int off = 32; off; off >>= 1) acc += __shfl_down(acc, off);
        if (lane == 0) scL[rsc][w] = (w <= t) ? acc : NEGF;
      }
      if (t > 0) {
        // LDS relay wait (no LLC traffic), then zhA
        while (__hip_atomic_load(&stampLow, __ATOMIC_ACQUIRE,
                                 __HIP_MEMORY_SCOPE_WORKGROUP) != (int)t)
          __builtin_amdgcn_s_sleep(1);
        float nv0 = nhLowL[0][lane], nv1 = nhLowL[1][lane];
        float z0 = 0.0f, z1 = 0.0f;
        #pragma unroll
        for (int k = 0; k < 64; ++k) {
          float w = wreg[128 + k];
          z0 = fmaf(bcast(nv0, k), w, z0);
          z1 = fmaf(bcast(nv1, k), w, z1);
        }
        zhA[0][c] = z0; zhA[1][c] = z1;
      }
    } else if (wv == 4) {
      if (t > 0) {
        const u64w* nb = nh_mb + ((size_t)parR * G_ + g) * (R_ * H_);
        // sole LLC poller for the 6 upper nh words; relay payloads to LDS.
        // zh itself runs AFTER B1 (overlapped with zx) on all upper waves.
        u64w nw[2][3];
        for (;;) {
          #pragma unroll
          for (int r = 0; r < 2; ++r)
            #pragma unroll
            for (int j = 0; j < 3; ++j)
              nw[r][j] = ld64(nb + (size_t)r * H_ + 64 + j * 64 + lane);
          int ok = 1;
          #pragma unroll
          for (int r = 0; r < 2; ++r)
            #pragma unroll
            for (int j = 0; j < 3; ++j)
              ok &= ((unsigned)nw[r][j] == stR);
          if (__all(ok)) break;
          __builtin_amdgcn_s_sleep(1);
        }
        #pragma unroll
        for (int r = 0; r < 2; ++r)
          #pragma unroll
          for (int j = 0; j < 3; ++j)
            nhUpL[r * 3 + j][lane] = hi32(nw[r][j]);
        // B1 publishes nhUpL to w5-7; no stamp needed. WAR-safe: w4 only
        // reaches next step's S0 after B2(t), by which time all upper
        // waves have consumed nhUpL in the S2' window.
      }
    }
    // w5-7: nothing in S0 (straight to B1)
    __syncthreads();                                   // B1

    // ===== S2': vtsel + zx + outputs (tid<256) || FULL zh + zring (tid>=256) =====
    if (tid < 256) {
      float vt0[2], vt1[2];
      #pragma unroll
      for (int r = 0; r < 2; ++r) {
        int bw = amax4(scL[r]);
        float il = invlen(bw);
        float v0 = 0.f, v1 = 0.f;
        #pragma unroll
        for (int c2 = 0; c2 < L_; ++c2)
          if (c2 <= bw) {
            v0 += ringVt[r][(t - c2) & 3][bw * 128 + lane];
            v1 += ringVt[r][(t - c2) & 3][bw * 128 + 64 + lane];
          }
        vt0[r] = v0 * il; vt1[r] = v1 * il;
      }
      float a0 = 0.f, a1 = 0.f;
      #pragma unroll
      for (int k = 0; k < 64; ++k) {
        float w0 = wreg[k], w1 = wreg[64 + k];
        a0 = fmaf(bcast(vt0[0], k), w0, a0);
        a1 = fmaf(bcast(vt0[1], k), w0, a1);
        a0 = fmaf(bcast(vt1[0], k), w1, a0);
        a1 = fmaf(bcast(vt1[1], k), w1, a1);
      }
      zxL[0][c] = a0; zxL[1][c] = a1;
      if (s == 0 && tid < R_) {
        int bw = amax4(scL[tid]);
        out[(row0 + tid) * T_ + t] = scL[tid][bw];
        out[B_ * T_ + (row0 + tid) * T_ + t] = (float)(bw + 1);
      }
    } else if (t > 0) {
      // full upper zh from relayed bits (identical j/k chain order),
      // then zring = zhA + z inline. Runs concurrently with zx above.
      float a0 = 0.0f, a1 = 0.0f;
      #pragma unroll
      for (int j = 0; j < 3; ++j) {
        float nv0 = nhUpL[j][lane], nv1 = nhUpL[3 + j][lane];
        #pragma unroll
        for (int k = 0; k < 64; ++k) {
          float w = wreg[j * 64 + k];
          a0 = fmaf(bcast(nv0, k), w, a0);
          a1 = fmaf(bcast(nv1, k), w, a1);
        }
      }
      int zs2 = (t - 1) & 3;
      zring[zs2][0][c] = zhA[0][c] + a0;
      zring[zs2][1][c] = zhA[1][c] + a1;
    }
    __syncthreads();                                   // B2

    // ===== S3 (waves 0-1): gates -> publish nh; in-wave pp -> publish =====
    // Waves 2-7 race into next step's S0 (stamps self-synchronize).
    if (tid < 128) {
      __builtin_amdgcn_s_setprio(1);
      int r = wv, hl = lane;
      int bw = amax4(scL[r]);
      int zs = (t - 1 - bw) & 3;
      float zg[4];
      #pragma unroll
      for (int gi = 0; gi < 4; ++gi) {
        int cc = gi * 64 + hl;
        zg[gi] = biasC[cc] + zring[zs][r][cc] + zxL[r][cc];
      }
      float cp = cring[zs][r][hl];
      float nc = cp * sigm(zg[2]) + sigm(zg[0]) * tanhf(zg[1]);
      float nh = tanhf(nc) * sigm(zg[3]);
      pub64(&nh_mb[((size_t)parW * G_ + g) * (R_ * H_) + (size_t)r * H_ + s * 64 + hl],
            nh, stW);
      cring[slot][r][hl] = nc;
      // pp partial over my 64 h-rows, in-wave (readlane broadcast + LDS predW)
      float p0 = 0.f, p1 = 0.f;
      #pragma unroll
      for (int kk = 0; kk < 64; ++kk) {
        float nb2 = bcast(nh, kk);
        p0 = fmaf(nb2, predWL[kk][lane], p0);
        p1 = fmaf(nb2, predWL[kk][lane + 64], p1);
      }
      u64w* pb = pp_mb + ((size_t)parW * G_ + g) * (S_ * R_ * 128)
               + (size_t)s * (R_ * 128) + (size_t)r * 128;
      pub64(pb + lane, p0, stW);
      pub64(pb + lane + 64, p1, stW);
      __builtin_amdgcn_s_setprio(0);
    }
    // no barrier: next iteration's B1 re-converges
  }
}

extern "C" void kernel_launch(void* const* d_in, const int* in_sizes, int n_in,
                              void* d_out, int out_size, void* d_ws, size_t ws_size,
                              hipStream_t stream) {
  const int*   chars     = (const int*)d_in[0];
  const float* char_emb  = (const float*)d_in[1];
  const float* reset_W   = (const float*)d_in[2];
  const float* reset_b   = (const float*)d_in[3];
  const float* com_W     = (const float*)d_in[4];
  const float* com_b     = (const float*)d_in[5];
  const float* lstm_k    = (const float*)d_in[6];
  const float* lstm_bias = (const float*)d_in[7];
  const float* pred_W    = (const float*)d_in[8];
  const float* pred_b    = (const float*)d_in[9];
  const float* score_U   = (const float*)d_in[10];
  const float* bos       = (const float*)d_in[11];

  char* ws = (char*)d_ws;
  float* Vtab = (float*)(ws + WS_VTAB);
  u64w* nh_mb = (u64w*)(ws + WS_NH);
  u64w* pp_mb = (u64w*)(ws + WS_PP);
  // No flags, no memset: the 0xAA poison word never matches a stamp in [1,256].

  vtab_kernel<<<V_, 512, 0, stream>>>(char_emb, reset_W, reset_b, com_W, com_b, Vtab);
  seq_kernel<<<256, 512, 0, stream>>>(chars, Vtab, lstm_k, lstm_bias, pred_W,
                                      pred_b, score_U, bos, (float*)d_out,
                                      nh_mb, pp_mb);
}

// Round 11
// 1963.476 us; speedup vs baseline: 1.0704x; 1.0704x over previous
//
#include <hip/hip_runtime.h>

#define B_ 128
#define T_ 256
#define L_ 4
#define DC_ 128
#define DW_ 128
#define H_ 256
#define V_ 6000
#define Z4_ 1024   // 4*H
#define S_ 4       // blocks per group (z-column split)
#define R_ 2       // batch rows per group
#define G_ 64      // groups = B/R
#define NEGF -1e30f

// d_ws layout (bytes). Stamps live inside data words — no flags, no memset.
#define WS_VTAB  4096                          // V*L*DW f32 = 12,288,000
#define WS_NH    (WS_VTAB + V_*L_*DW_*4)       // u64 [2][G][R][H]      = 512 KB
#define WS_PP    (WS_NH + (size_t)2*G_*R_*H_*8)// u64 [2][G][S][R][128] = 1 MB

typedef unsigned long long u64w;

__device__ __forceinline__ float sigm(float x) { return 1.0f / (1.0f + expf(-x)); }
__device__ __forceinline__ void pub64(u64w* p, float v, unsigned stamp) {
  u64w w = ((u64w)__float_as_uint(v) << 32) | (u64w)stamp;
  __hip_atomic_store(p, w, __ATOMIC_RELAXED, __HIP_MEMORY_SCOPE_AGENT);
}
__device__ __forceinline__ u64w ld64(const u64w* p) {
  return __hip_atomic_load(p, __ATOMIC_RELAXED, __HIP_MEMORY_SCOPE_AGENT);
}
__device__ __forceinline__ float hi32(u64w w) {
  return __uint_as_float((unsigned)(w >> 32));
}
// wave-broadcast from lane l via v_readlane (result lands in an SGPR — no VGPR cost)
__device__ __forceinline__ float bcast(float v, int l) {
  return __int_as_float(__builtin_amdgcn_readlane(__float_as_int(v), l));
}
__device__ __forceinline__ int amax4(const float* sc) {   // first-max-wins (jnp.argmax)
  float bs = sc[0]; int bw = 0;
  if (sc[1] > bs) { bs = sc[1]; bw = 1; }
  if (sc[2] > bs) { bs = sc[2]; bw = 2; }
  if (sc[3] > bs) { bs = sc[3]; bw = 3; }
  return bw;
}
__device__ __forceinline__ float invlen(int w) {
  return (w == 0) ? 1.0f : (w == 1) ? 0.5f : (w == 2) ? (1.0f / 3.0f) : 0.25f;
}

// ------------------------------------------------------------------
// Kernel 1: vocab composition table (unchanged — verified).
// ------------------------------------------------------------------
__global__ __launch_bounds__(512) void vtab_kernel(
    const float* __restrict__ char_emb, const float* __restrict__ reset_W,
    const float* __restrict__ reset_b, const float* __restrict__ com_W,
    const float* __restrict__ com_b, float* __restrict__ Vtab)
{
  const int v = blockIdx.x;
  const int tid = threadIdx.x;
  const int w = tid >> 7;
  const int e = tid & 127;
  __shared__ float emb[DC_];
  __shared__ float ge[L_][DC_];
  if (tid < DC_) emb[tid] = char_emb[v * DC_ + tid];
  __syncthreads();
  float acc = reset_b[w * DC_ + e];
  const float* W = reset_W + (size_t)w * DC_ * DC_;
  #pragma unroll 8
  for (int k = 0; k < DC_; ++k) acc = fmaf(emb[k], W[k * DC_ + e], acc);
  ge[w][e] = sigm(acc) * emb[e];
  __syncthreads();
  float acc2 = com_b[e];
  #pragma unroll 8
  for (int k = 0; k < DC_; ++k) acc2 = fmaf(ge[w][k], com_W[k * DW_ + e], acc2);
  Vtab[((size_t)v * L_ + w) * DW_ + e] = tanhf(acc2);
}

// ------------------------------------------------------------------
// Kernel 2: distributed scan, S=4 x R=2, blk = s*64+g, 512 threads.
// VERIFIED BEST = R8 structure (floor 1863us): 2 barriers/step, all
// scores hoisted into S0, LDS poll-relay dedup (w0 relays nh-lower,
// w4 relays nh-upper), zh/zx balanced across S0/S2' windows.
// R9 (zh after B1) regressed — R8's S0 overlap was already optimal.
// R10 (R=1, 512 blocks) deadlocked — occupancy is 1 block/CU at this
// register footprint (wreg[192] => ~320 regs/wave), so spin-sync
// designs are capped at 256 blocks.
// THIS ROUND (R11): R8 + busy-spin (no s_sleep) in w0/w1's nh and pp
// polls — the two detects on the serial cross-block chain. s_sleep(1)
// added a 64-cy wake quantum per detect. w4 and relay-waits keep
// their sleeps. No FP or sync-semantics change -> bit-identical.
// ------------------------------------------------------------------
__global__ __launch_bounds__(512, 2) void seq_kernel(
    const int* __restrict__ chars, const float* __restrict__ Vtab,
    const float* __restrict__ Kmat, const float* __restrict__ lstm_bias,
    const float* __restrict__ pred_W, const float* __restrict__ pred_b,
    const float* __restrict__ score_U, const float* __restrict__ bos,
    float* __restrict__ out, u64w* __restrict__ nh_mb, u64w* __restrict__ pp_mb)
{
  const int blk = blockIdx.x;
  const int s = blk >> 6;      // 0..3 column-split (partners stride 64 -> same XCD %8)
  const int g = blk & 63;      // group id
  const int tid = threadIdx.x;
  const int lane = tid & 63;
  const int wv = tid >> 6;
  const int c = tid & 255;     // my z-column (local)
  const int koff = (tid < 256) ? 0 : 192;
  const int colg = (c >> 6) * H_ + s * 64 + (c & 63);  // global z-column
  const int row0 = g * R_;

  // ---- weight registers: K[koff+i][colg], i = 0..191 ----
  float wreg[192];
  #pragma unroll
  for (int i = 0; i < 192; ++i)
    wreg[i] = Kmat[(size_t)(koff + i) * Z4_ + colg];

  __shared__ float ringVt[R_][4][512];      // 16 KB
  __shared__ float pring[4][R_][DW_];       // 4 KB
  __shared__ float zring[4][R_][256];       // 8 KB (also bos z scratch)
  __shared__ float cring[4][R_][64];        // 2 KB
  __shared__ float zhA[R_][256];            // 2 KB (type-A zh partials)
  __shared__ float zhB[R_][256];            // 2 KB (type-B zh partials)
  __shared__ float zxL[R_][256];            // 2 KB
  __shared__ float predWL[64][128];         // 32 KB (my pred_W slice)
  __shared__ float h1tmp[H_];               // 1 KB (init only)
  __shared__ int   charsL[R_][T_];          // 2 KB
  __shared__ float biasC[256], UL[128], pbL[128];
  __shared__ float scL[R_][L_];
  // LDS relay for deduped polls
  __shared__ float nhLowL[2][64];           // 0.5 KB (w0-relayed nh h[0:64])
  __shared__ float nhUpL[6][64];            // 1.5 KB (w4-relayed nh h[64:256])
  __shared__ int   stampLow, stampUp;

  // ---- one-time loads ----
  if (tid == 0) { stampLow = 0; stampUp = 0; }
  if (tid < 256) biasC[tid] = lstm_bias[(tid >> 6) * H_ + s * 64 + (tid & 63)];
  if (tid < 128) { UL[tid] = score_U[tid]; pbL[tid] = pred_b[tid]; }
  for (int i = tid; i < 64 * 128; i += 512)
    predWL[i >> 7][i & 127] = pred_W[(size_t)(s * 64 + (i >> 7)) * DW_ + (i & 127)];
  for (int i = tid; i < R_ * T_; i += 512)
    charsL[i >> 8][i & 255] = chars[(row0 + (i >> 8)) * T_ + (i & 255)];
  for (int i = tid; i < R_ * 4 * 512; i += 512) ((float*)ringVt)[i] = 0.0f;
  __syncthreads();

  // ---- bos step (x=bos, c0=h0=0): h1/c1, pred0, zh1 ----
  {
    float* zb = &zring[0][0][0];   // 1024-float scratch (slots 0-1)
    for (int c2 = tid; c2 < Z4_; c2 += 512) {
      float a = lstm_bias[c2];
      #pragma unroll 8
      for (int k = 0; k < DC_; ++k) a = fmaf(bos[k], Kmat[(size_t)k * Z4_ + c2], a);
      zb[c2] = a;
    }
    __syncthreads();
    if (tid < H_) {
      float zi = zb[tid], zj = zb[H_ + tid], zo = zb[3 * H_ + tid];
      float nc = sigm(zi) * tanhf(zj);
      float nh = tanhf(nc) * sigm(zo);
      h1tmp[tid] = nh;
      int hl = tid - s * 64;
      if (hl >= 0 && hl < 64) {
        #pragma unroll
        for (int q = 0; q < 4; ++q)
          #pragma unroll
          for (int r = 0; r < R_; ++r) cring[q][r][hl] = nc;
      }
    }
    __syncthreads();
    { // pred0 partials into zhA scratch (512 floats)
      int kq = tid >> 7, e = tid & 127;
      float a = 0.0f;
      #pragma unroll 8
      for (int k = kq * 64; k < kq * 64 + 64; ++k)
        a = fmaf(h1tmp[k], pred_W[(size_t)k * DW_ + e], a);
      ((float*)zhA)[kq * 128 + e] = a;
    }
    __syncthreads();
    if (tid < 128) {
      const float* pa = (const float*)zhA;
      float p = tanhf(pbL[tid] + pa[tid] + pa[128 + tid] + pa[256 + tid] + pa[384 + tid]);
      #pragma unroll
      for (int q = 0; q < 4; ++q)
        #pragma unroll
        for (int r = 0; r < R_; ++r) pring[q][r][tid] = p;
    }
    __syncthreads();   // pred0 partials consumed; zb consumed (h1 extracted)
    { // zh1 = Kh @ h1 via register weights (h1 same for both rows)
      float a = 0.0f;
      if (tid < 256) {
        #pragma unroll
        for (int k = 0; k < 64; ++k) a = fmaf(h1tmp[k], wreg[128 + k], a);
      } else {
        #pragma unroll
        for (int k = 0; k < 192; ++k) a = fmaf(h1tmp[64 + k], wreg[k], a);
      }
      __syncthreads();
      if (tid < 256) zhA[0][c] = a; else zhB[0][c] = a;
    }
    __syncthreads();
    if (tid < 256) {
      float z1 = zhA[0][tid] + zhB[0][tid];
      #pragma unroll
      for (int q = 0; q < 4; ++q)
        #pragma unroll
        for (int r = 0; r < R_; ++r) zring[q][r][tid] = z1;
    }
    __syncthreads();
  }

  // ---- scan ----
  for (int t = 0; t < T_; ++t) {
    const int slot = t & 3;
    const int parR = (t - 1) & 1;
    const int parW = t & 1;
    const unsigned stR = (unsigned)t;
    const unsigned stW = (unsigned)(t + 1);

    // ===== S0: polls + zh partials + pred + ALL scores =====
    if (wv < 2) {
      // w0/w1: nh poll (w0 relays) + zhA + pp poll + pred + score (r,0)
      const int r = wv;
      const float* vp0 = Vtab + (size_t)charsL[r][t] * 512;
      float vva = vp0[lane];          // c2=0 term, e=lane   (same bits as gather)
      float vvb = vp0[64 + lane];     // c2=0 term, e=lane+64
      if (t > 0) {
        const u64w* nb = nh_mb + ((size_t)parR * G_ + g) * (R_ * H_);
        u64w nw0, nw1;
        for (;;) {                    // busy-spin: critical detect, no sleep
          nw0 = ld64(nb + lane);
          nw1 = ld64(nb + H_ + lane);
          int ok = ((unsigned)nw0 == stR) & ((unsigned)nw1 == stR);
          if (__all(ok)) break;
        }
        float nv0 = hi32(nw0), nv1 = hi32(nw1);
        if (wv == 0) {   // relay payloads to w2-3 (exact bits)
          nhLowL[0][lane] = nv0;
          nhLowL[1][lane] = nv1;
          __hip_atomic_store(&stampLow, (int)t, __ATOMIC_RELEASE,
                             __HIP_MEMORY_SCOPE_WORKGROUP);
        }
        // zh(t-1) partial over h[0:64] via register weights (needs only nh)
        float z0 = 0.0f, z1 = 0.0f;
        #pragma unroll
        for (int k = 0; k < 64; ++k) {
          float w = wreg[128 + k];
          z0 = fmaf(bcast(nv0, k), w, z0);
          z1 = fmaf(bcast(nv1, k), w, z1);
        }
        zhA[0][c] = z0; zhA[1][c] = z1;
        // pp poll (partners publish pp ~400cy after nh; usually arrived)
        const u64w* ppb = pp_mb + ((size_t)parR * G_ + g) * (S_ * R_ * 128) + wv * 128;
        u64w pw0[S_], pw1[S_];
        for (;;) {                    // busy-spin: critical detect, no sleep
          #pragma unroll
          for (int sp = 0; sp < S_; ++sp) {
            pw0[sp] = ld64(ppb + (size_t)sp * (R_ * 128) + lane);
            pw1[sp] = ld64(ppb + (size_t)sp * (R_ * 128) + lane + 64);
          }
          int ok = 1;
          #pragma unroll
          for (int sp = 0; sp < S_; ++sp)
            ok &= ((unsigned)pw0[sp] == stR) & ((unsigned)pw1[sp] == stR);
          if (__all(ok)) break;
        }
        // pred(t-1) for row r=wv (sum order = sp 0..3, matches prior rounds)
        float a0 = pbL[lane], a1 = pbL[lane + 64];
        #pragma unroll
        for (int sp = 0; sp < S_; ++sp) {
          a0 += hi32(pw0[sp]);
          a1 += hi32(pw1[sp]);
        }
        int ps = (t - 1) & 3;
        pring[ps][wv][lane] = tanhf(a0);
        pring[ps][wv][lane + 64] = tanhf(a1);
      }
      { // score (r, w=0): needs only pring[(t-1)&3][r] (own wave) + vva/vvb
        int ps = (t - 1) & 3;
        float il = invlen(0);
        float acc = 0.0f;
        { float sa = vva;
          acc = fmaf(pring[ps][r][lane] + UL[lane], sa * il, acc); }
        { float sa = vvb;
          acc = fmaf(pring[ps][r][lane + 64] + UL[lane + 64], sa * il, acc); }
        #pragma unroll
        for (int off = 32; off; off >>= 1) acc += __shfl_down(acc, off);
        if (lane == 0) scL[r][0] = acc;    // w=0 <= t always
      }
    } else if (wv < 4) {
      // w2-3: Vt gather (LDS, both rows) + scores (rsc, w=1..3) hidden
      // under the relay wait, then zhA.
      const int rsc = wv - 2;
      int i2 = tid & 127;
      #pragma unroll
      for (int r = 0; r < R_; ++r) {
        const float* vp = Vtab + (size_t)charsL[r][t] * 512;
        #pragma unroll
        for (int q = 0; q < 4; ++q) ringVt[r][slot][q * 128 + i2] = vp[q * 128 + i2];
      }
      // register copies of the c2=0 terms for my score row (same bits)
      const float* vpr = Vtab + (size_t)charsL[rsc][t] * 512;
      float va[3], vb[3];
      #pragma unroll
      for (int w = 1; w <= 3; ++w) {
        va[w - 1] = vpr[w * 128 + lane];
        vb[w - 1] = vpr[w * 128 + 64 + lane];
      }
      // scores (rsc, w=1..3): read only prev-step pring/ringVt slots
      #pragma unroll
      for (int w = 1; w <= 3; ++w) {
        int ps = (t - 1 - w) & 3;
        float il = invlen(w);
        float acc = 0.0f;
        { float sa = va[w - 1];
          #pragma unroll
          for (int c2 = 1; c2 < L_; ++c2)
            if (c2 <= w) sa += ringVt[rsc][(t - c2) & 3][w * 128 + lane];
          acc = fmaf(pring[ps][rsc][lane] + UL[lane], sa * il, acc); }
        { float sa = vb[w - 1];
          #pragma unroll
          for (int c2 = 1; c2 < L_; ++c2)
            if (c2 <= w) sa += ringVt[rsc][(t - c2) & 3][w * 128 + 64 + lane];
          acc = fmaf(pring[ps][rsc][lane + 64] + UL[lane + 64], sa * il, acc); }
        #pragma unroll
        for (int off = 32; off; off >>= 1) acc += __shfl_down(acc, off);
        if (lane == 0) scL[rsc][w] = (w <= t) ? acc : NEGF;
      }
      if (t > 0) {
        // LDS relay wait (no LLC traffic), then zhA
        while (__hip_atomic_load(&stampLow, __ATOMIC_ACQUIRE,
                                 __HIP_MEMORY_SCOPE_WORKGROUP) != (int)t)
          __builtin_amdgcn_s_sleep(1);
        float nv0 = nhLowL[0][lane], nv1 = nhLowL[1][lane];
        float z0 = 0.0f, z1 = 0.0f;
        #pragma unroll
        for (int k = 0; k < 64; ++k) {
          float w = wreg[128 + k];
          z0 = fmaf(bcast(nv0, k), w, z0);
          z1 = fmaf(bcast(nv1, k), w, z1);
        }
        zhA[0][c] = z0; zhA[1][c] = z1;
      }
    } else if (wv == 4) {
      if (t > 0) {
        const u64w* nb = nh_mb + ((size_t)parR * G_ + g) * (R_ * H_);
        // sole LLC poller for the 6 upper nh words; relay to w5-7
        u64w nw[2][3];
        for (;;) {
          #pragma unroll
          for (int r = 0; r < 2; ++r)
            #pragma unroll
            for (int j = 0; j < 3; ++j)
              nw[r][j] = ld64(nb + (size_t)r * H_ + 64 + j * 64 + lane);
          int ok = 1;
          #pragma unroll
          for (int r = 0; r < 2; ++r)
            #pragma unroll
            for (int j = 0; j < 3; ++j)
              ok &= ((unsigned)nw[r][j] == stR);
          if (__all(ok)) break;
          __builtin_amdgcn_s_sleep(1);
        }
        #pragma unroll
        for (int r = 0; r < 2; ++r)
          #pragma unroll
          for (int j = 0; j < 3; ++j)
            nhUpL[r * 3 + j][lane] = hi32(nw[r][j]);
        __hip_atomic_store(&stampUp, (int)t, __ATOMIC_RELEASE,
                           __HIP_MEMORY_SCOPE_WORKGROUP);
        // zh from register copies (same chain order as all upper waves)
        float a0 = 0.0f, a1 = 0.0f;
        #pragma unroll
        for (int j = 0; j < 3; ++j) {
          float nv0 = hi32(nw[0][j]), nv1 = hi32(nw[1][j]);
          #pragma unroll
          for (int k = 0; k < 64; ++k) {
            float w = wreg[j * 64 + k];
            a0 = fmaf(bcast(nv0, k), w, a0);
            a1 = fmaf(bcast(nv1, k), w, a1);
          }
        }
        zhB[0][c] = a0; zhB[1][c] = a1;
      }
    } else {
      if (t > 0) {
        // w5-7: LDS relay wait, then identical zh chain from relayed bits
        while (__hip_atomic_load(&stampUp, __ATOMIC_ACQUIRE,
                                 __HIP_MEMORY_SCOPE_WORKGROUP) != (int)t)
          __builtin_amdgcn_s_sleep(1);
        float a0 = 0.0f, a1 = 0.0f;
        #pragma unroll
        for (int j = 0; j < 3; ++j) {
          float nv0 = nhUpL[j][lane], nv1 = nhUpL[3 + j][lane];
          #pragma unroll
          for (int k = 0; k < 64; ++k) {
            float w = wreg[j * 64 + k];
            a0 = fmaf(bcast(nv0, k), w, a0);
            a1 = fmaf(bcast(nv1, k), w, a1);
          }
        }
        zhB[0][c] = a0; zhB[1][c] = a1;
      }
    }
    __syncthreads();                                   // B1

    // ===== S2': vtsel + zx + outputs (tid<256) | zring reduce (tid>=256) =====
    if (tid < 256) {
      float vt0[2], vt1[2];
      #pragma unroll
      for (int r = 0; r < 2; ++r) {
        int bw = amax4(scL[r]);
        float il = invlen(bw);
        float v0 = 0.f, v1 = 0.f;
        #pragma unroll
        for (int c2 = 0; c2 < L_; ++c2)
          if (c2 <= bw) {
            v0 += ringVt[r][(t - c2) & 3][bw * 128 + lane];
            v1 += ringVt[r][(t - c2) & 3][bw * 128 + 64 + lane];
          }
        vt0[r] = v0 * il; vt1[r] = v1 * il;
      }
      float a0 = 0.f, a1 = 0.f;
      #pragma unroll
      for (int k = 0; k < 64; ++k) {
        float w0 = wreg[k], w1 = wreg[64 + k];
        a0 = fmaf(bcast(vt0[0], k), w0, a0);
        a1 = fmaf(bcast(vt0[1], k), w0, a1);
        a0 = fmaf(bcast(vt1[0], k), w1, a0);
        a1 = fmaf(bcast(vt1[1], k), w1, a1);
      }
      zxL[0][c] = a0; zxL[1][c] = a1;
      if (s == 0 && tid < R_) {
        int bw = amax4(scL[tid]);
        out[(row0 + tid) * T_ + t] = scL[tid][bw];
        out[B_ * T_ + (row0 + tid) * T_ + t] = (float)(bw + 1);
      }
    } else if (t > 0) {
      // zring(t-1) reduce (same values as before, any-thread pure function)
      zring[(t - 1) & 3][0][c] = zhA[0][c] + zhB[0][c];
      zring[(t - 1) & 3][1][c] = zhA[1][c] + zhB[1][c];
    }
    __syncthreads();                                   // B2

    // ===== S3 (waves 0-1): gates -> publish nh; in-wave pp -> publish =====
    // Waves 2-7 race into next step's S0 (stamps self-synchronize).
    if (tid < 128) {
      __builtin_amdgcn_s_setprio(1);
      int r = wv, hl = lane;
      int bw = amax4(scL[r]);
      int zs = (t - 1 - bw) & 3;
      float zg[4];
      #pragma unroll
      for (int gi = 0; gi < 4; ++gi) {
        int cc = gi * 64 + hl;
        zg[gi] = biasC[cc] + zring[zs][r][cc] + zxL[r][cc];
      }
      float cp = cring[zs][r][hl];
      float nc = cp * sigm(zg[2]) + sigm(zg[0]) * tanhf(zg[1]);
      float nh = tanhf(nc) * sigm(zg[3]);
      pub64(&nh_mb[((size_t)parW * G_ + g) * (R_ * H_) + (size_t)r * H_ + s * 64 + hl],
            nh, stW);
      cring[slot][r][hl] = nc;
      // pp partial over my 64 h-rows, in-wave (readlane broadcast + LDS predW)
      float p0 = 0.f, p1 = 0.f;
      #pragma unroll
      for (int kk = 0; kk < 64; ++kk) {
        float nb2 = bcast(nh, kk);
        p0 = fmaf(nb2, predWL[kk][lane], p0);
        p1 = fmaf(nb2, predWL[kk][lane + 64], p1);
      }
      u64w* pb = pp_mb + ((size_t)parW * G_ + g) * (S_ * R_ * 128)
               + (size_t)s * (R_ * 128) + (size_t)r * 128;
      pub64(pb + lane, p0, stW);
      pub64(pb + lane + 64, p1, stW);
      __builtin_amdgcn_s_setprio(0);
    }
    // no barrier: next iteration's B1 re-converges
  }
}

extern "C" void kernel_launch(void* const* d_in, const int* in_sizes, int n_in,
                              void* d_out, int out_size, void* d_ws, size_t ws_size,
                              hipStream_t stream) {
  const int*   chars     = (const int*)d_in[0];
  const float* char_emb  = (const float*)d_in[1];
  const float* reset_W   = (const float*)d_in[2];
  const float* reset_b   = (const float*)d_in[3];
  const float* com_W     = (const float*)d_in[4];
  const float* com_b     = (const float*)d_in[5];
  const float* lstm_k    = (const float*)d_in[6];
  const float* lstm_bias = (const float*)d_in[7];
  const float* pred_W    = (const float*)d_in[8];
  const float* pred_b    = (const float*)d_in[9];
  const float* score_U   = (const float*)d_in[10];
  const float* bos       = (const float*)d_in[11];

  char* ws = (char*)d_ws;
  float* Vtab = (float*)(ws + WS_VTAB);
  u64w* nh_mb = (u64w*)(ws + WS_NH);
  u64w* pp_mb = (u64w*)(ws + WS_PP);
  // No flags, no memset: the 0xAA poison word never matches a stamp in [1,256].

  vtab_kernel<<<V_, 512, 0, stream>>>(char_emb, reset_W, reset_b, com_W, com_b, Vtab);
  seq_kernel<<<256, 512, 0, stream>>>(chars, Vtab, lstm_k, lstm_bias, pred_W,
                                      pred_b, score_U, bos, (float*)d_out,
                                      nh_mb, pp_mb);
}